// Round 4
// baseline (862.900 us; speedup 1.0000x reference)
//
#include <hip/hip_runtime.h>
#include <stdint.h>

#define NNODES 50000
#define NEDGES 400000
#define EMB 128
#define KD 896
#define BM 128

typedef __attribute__((ext_vector_type(8))) short bf16x8;
typedef __attribute__((ext_vector_type(4))) float f32x4;

__device__ __forceinline__ short f2bf(float f) {
  union { float f; uint32_t u; } v; v.f = f;
  uint32_t r = v.u + 0x7FFFu + ((v.u >> 16) & 1u);
  return (short)(r >> 16);
}
__device__ __forceinline__ float bf2f(short s) {
  union { uint32_t u; float f; } v; v.u = ((uint32_t)(uint16_t)s) << 16;
  return v.f;
}
__device__ __forceinline__ float fast_gelu(float x) {
  float x2 = x * x;
  float y = x * (0.7978845608f + 0.03567740814f * x2);
  float e = __expf(2.0f * y);
  float r = __builtin_amdgcn_rcpf(1.0f + e);
  return x - x * r;     // 0.5x(1+tanh(y)); saturates correctly at +/-inf
}

// B layout: chunk c = sidx*4 + wn*2 + f  (sidx = ((i*2+fnh)*4+kk), 0..55)
// element: short idx = c*512 + lane*8 + m
// value  = W2[(kk*32 + (lane>>4)*8 + m)*896 + i*128 + (wn*4+fnh*2+f)*16 + (lane&15)]
__global__ void prep_B(const float* __restrict__ W2, short* __restrict__ Bp) {
  int idx = blockIdx.x * 256 + threadIdx.x;   // 448*256 = 114688 exact
  int m = idx & 7, l = (idx >> 3) & 63, c = idx >> 9;
  int sidx = c >> 2, wn = (c >> 1) & 1, f = c & 1;
  int p = sidx >> 2, kk = sidx & 3, i = p >> 1, fnh = p & 1;
  int o = (wn * 4 + fnh * 2 + f) * 16 + (l & 15);
  int k = kk * 32 + (l >> 4) * 8 + m;
  Bp[idx] = f2bf(W2[k * KD + i * EMB + o]);
}

// W1p fragment layout: idx = (nf*64 + lane)*8 + m
// kseg0/1 -> W1_hi[m][col] (paired with ea_hi / ea_lo), kseg2 -> W1_lo, kseg3 -> 0
__global__ void prep_W1(const float* __restrict__ W1f, short* __restrict__ W1p) {
  int idx = blockIdx.x * 256 + threadIdx.x;   // 16*256 = 4096
  int m = idx & 7, lane = (idx >> 3) & 63, nf = idx >> 9;
  int col = nf * 16 + (lane & 15), kseg = lane >> 4;
  short outv = 0;
  if (m < 6 && kseg < 3) {
    float wv = W1f[m * EMB + col];
    short hi = f2bf(wv);
    outv = (kseg == 2) ? f2bf(wv - bf2f(hi)) : hi;
  }
  W1p[idx] = outv;
}

__global__ __launch_bounds__(256, 3)
void nnconv_main(const float* __restrict__ x,
                 const int* __restrict__ ei,
                 const float* __restrict__ ea,
                 const float* __restrict__ b1,
                 const float* __restrict__ b2,
                 const short* __restrict__ Bp,
                 const short* __restrict__ W1p,
                 float* __restrict__ cnt,
                 float* __restrict__ out) {
  __shared__ __align__(16) short h_s[BM * EMB];   // 32KB, 4-bit XOR swizzled
  __shared__ __align__(16) float x_s[BM][9];
  __shared__ __align__(16) float ea_s[BM * 6];
  __shared__ int dst_s[BM];

  const int t = threadIdx.x;
  const int lane = t & 63;
  const int w = t >> 6;
  const int wm = w >> 1, wn = w & 1;
  const int rowA = lane & 15;
  const int kseg = lane >> 4;
  const int eb = blockIdx.x * BM;

  // ---- early B prefetch: steps 0..3 (consumed after phase1) ----
  const char* BpB = (const char*)Bp + lane * 16 + wn * 2048;
  bf16x8 bfr[4][2];
#pragma unroll
  for (int s = 0; s < 4; ++s)
#pragma unroll
    for (int f = 0; f < 2; ++f)
      bfr[s][f] = *(const bf16x8*)(BpB + (((size_t)s * 4 + f) << 10));

  // ---- phase 0: stage ea, gather x, dst, degree count ----
  if (t < 192)
    *(float4*)&ea_s[t * 4] = *(const float4*)&ea[(size_t)eb * 6 + t * 4];
  if (t < BM) {
    int s = ei[eb + t];
    int d = ei[NEDGES + eb + t];
    dst_s[t] = d;
#pragma unroll
    for (int i = 0; i < 7; ++i) x_s[t][i] = x[s * 7 + i];
    atomicAdd(&cnt[d], 1.0f);
  }
  __syncthreads();

  // ---- phase 1: h = gelu(ea@W1 + b1) via MFMA (hi/lo exact split in one K=32) ----
  {
    bf16x8 aef[2];
#pragma unroll
    for (int fm2 = 0; fm2 < 2; ++fm2) {
      int re = w * 32 + fm2 * 16 + rowA;
      bf16x8 av = (bf16x8){0, 0, 0, 0, 0, 0, 0, 0};
#pragma unroll
      for (int q = 0; q < 6; ++q) {
        float eq = ea_s[re * 6 + q];
        short hq = f2bf(eq);
        short lq = f2bf(eq - bf2f(hq));
        short v = (kseg == 1) ? lq : hq;
        av[q] = (kseg == 3) ? (short)0 : v;
      }
      aef[fm2] = av;
    }
#pragma unroll
    for (int half = 0; half < 2; ++half) {
      bf16x8 wf[4];
      f32x4 cf[2][4];
#pragma unroll
      for (int j = 0; j < 4; ++j)
        wf[j] = *(const bf16x8*)(W1p + ((half * 4 + j) * 64 + lane) * 8);
#pragma unroll
      for (int j = 0; j < 4; ++j) {
        float bc = b1[(half * 4 + j) * 16 + rowA];
        f32x4 ci = (f32x4){bc, bc, bc, bc};
#pragma unroll
        for (int fm2 = 0; fm2 < 2; ++fm2)
          cf[fm2][j] = __builtin_amdgcn_mfma_f32_16x16x32_bf16(aef[fm2], wf[j], ci, 0, 0, 0);
      }
#pragma unroll
      for (int fm2 = 0; fm2 < 2; ++fm2)
#pragma unroll
        for (int j = 0; j < 4; ++j)
#pragma unroll
          for (int r = 0; r < 4; ++r) {
            int row = w * 32 + fm2 * 16 + kseg * 4 + r;
            int col = (half * 4 + j) * 16 + rowA;
            short hv = f2bf(fast_gelu(cf[fm2][j][r]));
            *(short*)((char*)h_s + row * 256 + ((col * 2) ^ ((row & 15) << 4))) = hv;
          }
    }
  }
  __syncthreads();

  // ---- K-loop: barrier-free, fn-halved (tmp 32 regs), pair-prefetch dist 2 ----
  f32x4 acc[4][4];
#pragma unroll
  for (int a = 0; a < 4; ++a)
#pragma unroll
    for (int b = 0; b < 4; ++b) acc[a][b] = (f32x4){0.f, 0.f, 0.f, 0.f};

#pragma unroll 1
  for (int i = 0; i < 7; ++i) {
#pragma unroll
    for (int fnh = 0; fnh < 2; ++fnh) {
      const int p = i * 2 + fnh;
      const int s0 = p * 4;
      f32x4 tmp[4][2];
#pragma unroll
      for (int a = 0; a < 4; ++a) {
        tmp[a][0] = (f32x4){0.f, 0.f, 0.f, 0.f};
        tmp[a][1] = (f32x4){0.f, 0.f, 0.f, 0.f};
      }
#pragma unroll
      for (int kk = 0; kk < 4; ++kk) {
        bf16x8 af[4];
#pragma unroll
        for (int fm = 0; fm < 4; ++fm) {
          int row = wm * 64 + fm * 16 + rowA;
          int col = (kk * 64 + kseg * 16) ^ ((row & 15) << 4);
          af[fm] = *(const bf16x8*)((const char*)h_s + row * 256 + col);
        }
#pragma unroll
        for (int fm = 0; fm < 4; ++fm) {
          tmp[fm][0] = __builtin_amdgcn_mfma_f32_16x16x32_bf16(af[fm], bfr[kk][0], tmp[fm][0], 0, 0, 0);
          tmp[fm][1] = __builtin_amdgcn_mfma_f32_16x16x32_bf16(af[fm], bfr[kk][1], tmp[fm][1], 0, 0, 0);
        }
        if ((kk == 1 || kk == 3) && p < 13) {
          const int sn = s0 + 4 + ((kk == 3) ? 2 : 0);
          const int slot = (kk == 1) ? 0 : 2;
#pragma unroll
          for (int u = 0; u < 2; ++u)
#pragma unroll
            for (int f = 0; f < 2; ++f)
              bfr[slot + u][f] = *(const bf16x8*)(BpB + (((size_t)(sn + u) * 4 + f) << 10));
        }
      }
      // scale-accumulate by x[:, i]
#pragma unroll
      for (int fm = 0; fm < 4; ++fm)
#pragma unroll
        for (int r = 0; r < 4; ++r) {
          float xv = x_s[wm * 64 + fm * 16 + kseg * 4 + r][i];
          acc[fm][fnh * 2 + 0][r] += xv * tmp[fm][0][r];
          acc[fm][fnh * 2 + 1][r] += xv * tmp[fm][1][r];
        }
    }
  }

  // ---- epilogue: + x·b2 term, atomic scatter ----
  const int colA = rowA;
  float bb[4][7];
#pragma unroll
  for (int j = 0; j < 4; ++j)
#pragma unroll
    for (int i = 0; i < 7; ++i)
      bb[j][i] = b2[i * EMB + wn * 64 + j * 16 + colA];

#pragma unroll
  for (int fm = 0; fm < 4; ++fm)
#pragma unroll
    for (int r = 0; r < 4; ++r) {
      const int row = wm * 64 + fm * 16 + kseg * 4 + r;
      float xr[7];
#pragma unroll
      for (int i = 0; i < 7; ++i) xr[i] = x_s[row][i];
      const int d = dst_s[row];
      float* op = out + (size_t)d * EMB + wn * 64 + colA;
#pragma unroll
      for (int j = 0; j < 4; ++j) {
        float v = acc[fm][j][r];
#pragma unroll
        for (int i = 0; i < 7; ++i) v += xr[i] * bb[j][i];
        atomicAdd(op + j * 16, v);
      }
    }
}

// out = out/clip(cnt,1) + x@root + bias
__global__ void finalize(const float* __restrict__ x, const float* __restrict__ root,
                         const float* __restrict__ bias, const float* __restrict__ cnt,
                         float* __restrict__ out) {
  int idx = blockIdx.x * 256 + threadIdx.x;
  int n = idx >> 7, o = idx & 127;
  float c = fmaxf(cnt[n], 1.0f);
  float v = out[idx] / c + bias[o];
#pragma unroll
  for (int i = 0; i < 7; ++i) v += x[n * 7 + i] * root[i * EMB + o];
  out[idx] = v;
}

extern "C" void kernel_launch(void* const* d_in, const int* in_sizes, int n_in,
                              void* d_out, int out_size, void* d_ws, size_t ws_size,
                              hipStream_t stream) {
  const float* x    = (const float*)d_in[0];
  const int*   ei   = (const int*)d_in[1];
  const float* ea   = (const float*)d_in[2];
  const float* W1   = (const float*)d_in[3];
  const float* b1   = (const float*)d_in[4];
  const float* W2   = (const float*)d_in[5];
  const float* b2   = (const float*)d_in[6];
  const float* root = (const float*)d_in[7];
  const float* bias = (const float*)d_in[8];
  float* out = (float*)d_out;

  short* Bp  = (short*)d_ws;                                   // 229376 B
  short* W1p = (short*)((char*)d_ws + 128 * KD * 2);           // 8192 B
  float* cnt = (float*)((char*)d_ws + 128 * KD * 2 + 8192);    // 200 KB

  hipMemsetAsync(out, 0, (size_t)NNODES * EMB * sizeof(float), stream);
  hipMemsetAsync(cnt, 0, (size_t)NNODES * sizeof(float), stream);
  prep_B<<<448, 256, 0, stream>>>(W2, Bp);
  prep_W1<<<16, 256, 0, stream>>>(W1, W1p);
  nnconv_main<<<NEDGES / BM, 256, 0, stream>>>(x, ei, ea, b1, b2, Bp, W1p, cnt, out);
  finalize<<<NNODES * EMB / 256, 256, 0, stream>>>(x, root, bias, cnt, out);
}

// Round 7
// 301.260 us; speedup vs baseline: 2.8643x; 2.8643x over previous
//
#include <hip/hip_runtime.h>
#include <stdint.h>

#define NNODES 50000
#define NEDGES 400000
#define EMB 128
#define KD 896
#define BM 128

typedef __attribute__((ext_vector_type(8))) short bf16x8;
typedef __attribute__((ext_vector_type(4))) float f32x4;

__device__ __forceinline__ short f2bf(float f) {
  union { float f; uint32_t u; } v; v.f = f;
  uint32_t r = v.u + 0x7FFFu + ((v.u >> 16) & 1u);
  return (short)(r >> 16);
}
__device__ __forceinline__ float bf2f(short s) {
  union { uint32_t u; float f; } v; v.u = ((uint32_t)(uint16_t)s) << 16;
  return v.f;
}
__device__ __forceinline__ float fast_gelu(float x) {
  float x2 = x * x;
  float y = x * (0.7978845608f + 0.03567740814f * x2);
  float e = __expf(2.0f * y);
  float r = __builtin_amdgcn_rcpf(1.0f + e);
  return x - x * r;     // 0.5x(1+tanh(y)); saturates correctly
}

// B layout (unchanged from R2/R3, validated): chunk c = sidx*4 + wn*2 + f,
// sidx = (i*2+fh)*4+kk; element: short idx = c*512 + lane*8 + m
// value = W2[(kk*32 + (lane>>4)*8 + m)*896 + i*128 + (wn*4+fh*2+f)*16 + (lane&15)]
__global__ void prep_B(const float* __restrict__ W2, short* __restrict__ Bp) {
  int idx = blockIdx.x * 256 + threadIdx.x;   // 448*256 = 114688 exact
  int m = idx & 7, l = (idx >> 3) & 63, c = idx >> 9;
  int sidx = c >> 2, wn = (c >> 1) & 1, f = c & 1;
  int p = sidx >> 2, kk = sidx & 3, i = p >> 1, fnh = p & 1;
  int o = (wn * 4 + fnh * 2 + f) * 16 + (l & 15);
  int k = kk * 32 + (l >> 4) * 8 + m;
  Bp[idx] = f2bf(W2[k * KD + i * EMB + o]);
}

// W1p: phase-1 A-operand frags: idx = (mt*64 + lane)*8 + m; o = mt*16+(lane&15)
// kseg0/1: W1_hi[m][o]; kseg2: W1_lo[m][o]; kseg3: m0=b1_hi[o], m1=b1_lo[o]
__global__ void prep_W1(const float* __restrict__ W1f, const float* __restrict__ b1,
                        short* __restrict__ W1p) {
  int idx = blockIdx.x * 256 + threadIdx.x;   // 16*256 = 4096
  int m = idx & 7, l = (idx >> 3) & 63, mt = idx >> 9;
  int o = mt * 16 + (l & 15), kseg = l >> 4;
  short v = 0;
  if (kseg < 2) {
    if (m < 6) v = f2bf(W1f[m * EMB + o]);
  } else if (kseg == 2) {
    if (m < 6) { float wv = W1f[m * EMB + o]; short hi = f2bf(wv); v = f2bf(wv - bf2f(hi)); }
  } else {
    if (m == 0) v = f2bf(b1[o]);
    else if (m == 1) { float bv = b1[o]; short hi = f2bf(bv); v = f2bf(bv - bf2f(hi)); }
  }
  W1p[idx] = v;
}

__global__ __launch_bounds__(256, 2)
void nnconv_main(const float* __restrict__ x,
                 const int* __restrict__ ei,
                 const float* __restrict__ ea,
                 const float* __restrict__ b2,
                 const short* __restrict__ Bp,
                 const short* __restrict__ W1p,
                 float* __restrict__ cnt,
                 float* __restrict__ out) {
  __shared__ __align__(16) short h_s[BM * EMB];   // 32KB, XOR-swizzled rows
  __shared__ __align__(16) float x_t[7][132];     // transposed x gather, padded
  __shared__ __align__(16) float ea_s[BM * 6];
  __shared__ int dst_s[BM];

  const int t = threadIdx.x;
  const int lane = t & 63;
  const int w = t >> 6;
  const int wm = w >> 1, wn = w & 1;
  const int rowA = lane & 15;
  const int kseg = lane >> 4;
  const int eb = blockIdx.x * BM;
  const char* BpB = (const char*)Bp + wn * 2048 + lane * 16;

  // ---- early B prefetch: chunk (fh=0,i=0) = sidx 0..3 ----
  bf16x8 bcur[4][2];
#pragma unroll
  for (int kk = 0; kk < 4; ++kk)
#pragma unroll
    for (int f = 0; f < 2; ++f)
      bcur[kk][f] = *(const bf16x8*)(BpB + (((size_t)kk * 4 + f) << 10));

  // ---- phase 0 ----
  if (t < 192)
    *(float4*)&ea_s[t * 4] = *(const float4*)&ea[(size_t)eb * 6 + t * 4];
  if (t < BM) {
    int s = ei[eb + t];
    int d = ei[NEDGES + eb + t];
    dst_s[t] = d;
#pragma unroll
    for (int i = 0; i < 7; ++i) x_t[i][t] = x[s * 7 + i];
    atomicAdd(&cnt[d], 1.0f);
  }
  __syncthreads();

  // ---- phase 1: h = gelu(ea@W1+b1), swapped operands: D[o][edge] ----
  {
    bf16x8 wa[8];
#pragma unroll
    for (int mt = 0; mt < 8; ++mt)
      wa[mt] = *(const bf16x8*)(W1p + (mt * 64 + lane) * 8);
#pragma unroll
    for (int et2 = 0; et2 < 2; ++et2) {
      const int e = w * 32 + et2 * 16 + rowA;
      bf16x8 be = (bf16x8){0, 0, 0, 0, 0, 0, 0, 0};
      if (kseg == 3) {
        be[0] = f2bf(1.0f); be[1] = f2bf(1.0f);
      } else {
#pragma unroll
        for (int q = 0; q < 6; ++q) {
          float v = ea_s[e * 6 + q];
          short hi = f2bf(v);
          be[q] = (kseg == 1) ? f2bf(v - bf2f(hi)) : hi;
        }
      }
      const int swz = (e & 15) << 4;
#pragma unroll
      for (int mt = 0; mt < 8; ++mt) {
        f32x4 d = __builtin_amdgcn_mfma_f32_16x16x32_bf16(
            wa[mt], be, (f32x4){0.f, 0.f, 0.f, 0.f}, 0, 0, 0);
        uint32_t h0 = (uint16_t)f2bf(fast_gelu(d[0]));
        uint32_t h1 = (uint16_t)f2bf(fast_gelu(d[1]));
        uint32_t h2 = (uint16_t)f2bf(fast_gelu(d[2]));
        uint32_t h3 = (uint16_t)f2bf(fast_gelu(d[3]));
        uint2 u; u.x = h0 | (h1 << 16); u.y = h2 | (h3 << 16);
        int off = (mt * 32 + kseg * 8) ^ swz;
        *(uint2*)((char*)h_s + e * 256 + off) = u;
      }
    }
  }
  __syncthreads();

  // ---- load A fragments ONCE (i-invariant): 16 frags = 64 VGPR ----
  bf16x8 A[4][4];
#pragma unroll
  for (int kk = 0; kk < 4; ++kk)
#pragma unroll
    for (int fm = 0; fm < 4; ++fm) {
      int row = wm * 64 + fm * 16 + rowA;
      int off = (kk * 64 + kseg * 16) ^ (rowA << 4);
      A[kk][fm] = *(const bf16x8*)((const char*)h_s + row * 256 + off);
    }

  // ---- K-loop: fh halves; barrier-free; B refilled in place after last use ----
#pragma unroll
  for (int fh = 0; fh < 2; ++fh) {
    f32x4 acc2[4][2];
#pragma unroll
    for (int a = 0; a < 4; ++a) {
      acc2[a][0] = (f32x4){0.f, 0.f, 0.f, 0.f};
      acc2[a][1] = (f32x4){0.f, 0.f, 0.f, 0.f};
    }
#pragma unroll 1
    for (int i = 0; i < 7; ++i) {
      // b2 fold (consumed only after MFMAs -> latency hidden)
      float b2v0 = b2[i * EMB + wn * 64 + fh * 32 + rowA];
      float b2v1 = b2[i * EMB + wn * 64 + fh * 32 + 16 + rowA];
      // next chunk base sidx
      int nsidx;
      if (fh == 0) nsidx = (i < 6) ? (i + 1) * 8 : 4;        // (0,i+1) or (1,0)
      else         nsidx = (i < 6) ? (i + 1) * 8 + 4 : 52;   // (1,i+1) or clamp

      f32x4 tmp[4][2];
      const f32x4 zz = (f32x4){0.f, 0.f, 0.f, 0.f};
#pragma unroll
      for (int fm = 0; fm < 4; ++fm) {
        tmp[fm][0] = __builtin_amdgcn_mfma_f32_16x16x32_bf16(A[0][fm], bcur[0][0], zz, 0, 0, 0);
        tmp[fm][1] = __builtin_amdgcn_mfma_f32_16x16x32_bf16(A[0][fm], bcur[0][1], zz, 0, 0, 0);
      }
      bcur[0][0] = *(const bf16x8*)(BpB + (((size_t)(nsidx + 0) * 4 + 0) << 10));
      bcur[0][1] = *(const bf16x8*)(BpB + (((size_t)(nsidx + 0) * 4 + 1) << 10));
#pragma unroll
      for (int kk = 1; kk < 4; ++kk) {
#pragma unroll
        for (int fm = 0; fm < 4; ++fm) {
          tmp[fm][0] = __builtin_amdgcn_mfma_f32_16x16x32_bf16(A[kk][fm], bcur[kk][0], tmp[fm][0], 0, 0, 0);
          tmp[fm][1] = __builtin_amdgcn_mfma_f32_16x16x32_bf16(A[kk][fm], bcur[kk][1], tmp[fm][1], 0, 0, 0);
        }
        bcur[kk][0] = *(const bf16x8*)(BpB + (((size_t)(nsidx + kk) * 4 + 0) << 10));
        bcur[kk][1] = *(const bf16x8*)(BpB + (((size_t)(nsidx + kk) * 4 + 1) << 10));
      }
      // scale by x[:,i] (+ folded b2)
#pragma unroll
      for (int fm = 0; fm < 4; ++fm) {
        f32x4 xv = *(const f32x4*)&x_t[i][wm * 64 + fm * 16 + kseg * 4];
#pragma unroll
        for (int r = 0; r < 4; ++r) {
          acc2[fm][0][r] += xv[r] * (tmp[fm][0][r] + b2v0);
          acc2[fm][1][r] += xv[r] * (tmp[fm][1][r] + b2v1);
        }
      }
    }
    // ---- epilogue half: pure atomic scatter ----
#pragma unroll
    for (int fm = 0; fm < 4; ++fm)
#pragma unroll
      for (int r = 0; r < 4; ++r) {
        const int row = wm * 64 + fm * 16 + kseg * 4 + r;
        const int d = dst_s[row];
        float* op = out + (size_t)d * EMB + wn * 64 + fh * 32 + rowA;
        atomicAdd(op, acc2[fm][0][r]);
        atomicAdd(op + 16, acc2[fm][1][r]);
      }
  }
}

// out = out/clip(cnt,1) + x@root + bias
__global__ void finalize(const float* __restrict__ x, const float* __restrict__ root,
                         const float* __restrict__ bias, const float* __restrict__ cnt,
                         float* __restrict__ out) {
  int idx = blockIdx.x * 256 + threadIdx.x;
  int n = idx >> 7, o = idx & 127;
  float c = fmaxf(cnt[n], 1.0f);
  float v = out[idx] / c + bias[o];
#pragma unroll
  for (int i = 0; i < 7; ++i) v += x[n * 7 + i] * root[i * EMB + o];
  out[idx] = v;
}

extern "C" void kernel_launch(void* const* d_in, const int* in_sizes, int n_in,
                              void* d_out, int out_size, void* d_ws, size_t ws_size,
                              hipStream_t stream) {
  const float* x    = (const float*)d_in[0];
  const int*   ei   = (const int*)d_in[1];
  const float* ea   = (const float*)d_in[2];
  const float* W1   = (const float*)d_in[3];
  const float* b1   = (const float*)d_in[4];
  const float* W2   = (const float*)d_in[5];
  const float* b2   = (const float*)d_in[6];
  const float* root = (const float*)d_in[7];
  const float* bias = (const float*)d_in[8];
  float* out = (float*)d_out;

  short* Bp  = (short*)d_ws;                                   // 229376 B
  short* W1p = (short*)((char*)d_ws + 128 * KD * 2);           // 8192 B
  float* cnt = (float*)((char*)d_ws + 128 * KD * 2 + 8192);    // 200 KB

  hipMemsetAsync(out, 0, (size_t)NNODES * EMB * sizeof(float), stream);
  hipMemsetAsync(cnt, 0, (size_t)NNODES * sizeof(float), stream);
  prep_B<<<448, 256, 0, stream>>>(W2, Bp);
  prep_W1<<<16, 256, 0, stream>>>(W1, b1, W1p);
  nnconv_main<<<NEDGES / BM, 256, 0, stream>>>(x, ei, ea, b2, Bp, W1p, cnt, out);
  finalize<<<NNODES * EMB / 256, 256, 0, stream>>>(x, root, bias, cnt, out);
}